// Round 4
// baseline (118.751 us; speedup 1.0000x reference)
//
#include <hip/hip_runtime.h>

// Problem constants
#define IC 8
#define NC 2304      // 48*48 coarse pixels (theta rows == phi cols, coarse)
#define NF 9216      // 96*96 fine pixels
#define Z_ELEMS 147456    // 16*96*96
#define XPAN_ELEMS 589824 // 16*192*192

typedef unsigned int uint_t;

// ---------------------------------------------------------------------------
// Kernel 1:
//   blocks 0..8     theta conv3x3 s2 p1 (one thread per coarse output pixel)
//   blocks 9..44    phi conv3x3 s2 p1 (one thread per PRE-POOL pixel) + shfl-maxpool
//   blocks 45..188  g conv1x1 (one thread per PRE-POOL pixel) + shfl-maxpool
//   blocks 189..764 x_pan passthrough copy (uint4)
// All loads unconditional (clamp+select masks) so the compiler batches them;
// weights fetched with block-uniform indices -> scalar loads (K$), no LDS.
// ---------------------------------------------------------------------------
__global__ __launch_bounds__(256) void k1_prep(
    const float* __restrict__ xms,    // (16,96,96)
    const float* __restrict__ hppan,  // (16,192,192)
    const float* __restrict__ xpan,   // (16,192,192)
    const float* __restrict__ gw, const float* __restrict__ gb,
    const float* __restrict__ thw, const float* __restrict__ thb,
    const float* __restrict__ phw, const float* __restrict__ phb,
    float* __restrict__ theta_c,  // [2304][8]
    float* __restrict__ phi_c,    // [2304][8]
    float* __restrict__ gmat,     // [9216][8]
    float* __restrict__ xpan_out)
{
    const int b = blockIdx.x;
    const int tid = threadIdx.x;

    if (b < 9) {
        // --- theta: (16,96,96) -> (8,48,48), one thread per output pixel ---
        int pix = b * 256 + tid;              // 0..2303
        int r = pix / 48, c = pix % 48;
        int ir0 = 2 * r - 1, ic0 = 2 * c - 1;
        bool rok = (r > 0), cok = (c > 0);
        float acc[8];
        #pragma unroll
        for (int co = 0; co < 8; ++co) acc[co] = thb[co];
        #pragma unroll 4
        for (int ci = 0; ci < 16; ++ci) {
            const float* base = xms + ci * 9216;
            float xv[9];
            #pragma unroll
            for (int dr = 0; dr < 3; ++dr) {
                #pragma unroll
                for (int dc = 0; dc < 3; ++dc) {
                    bool ok = (dr > 0 || rok) && (dc > 0 || cok);
                    int off = (ir0 + dr) * 96 + (ic0 + dc);
                    float v = base[ok ? off : 0];
                    xv[dr * 3 + dc] = ok ? v : 0.0f;
                }
            }
            #pragma unroll
            for (int tap = 0; tap < 9; ++tap) {
                #pragma unroll
                for (int co = 0; co < 8; ++co)
                    acc[co] += thw[co * 144 + ci * 9 + tap] * xv[tap];
            }
        }
        #pragma unroll
        for (int co = 0; co < 8; ++co) theta_c[pix * 8 + co] = acc[co];
    } else if (b < 45) {
        // --- phi: (16,192,192) -> conv (8,96,96) -> pool (8,48,48) ---
        // one thread per pre-pool pixel; pool-mates are lane quads
        int idx = (b - 9) * 256 + tid;        // 0..9215
        int cp = idx >> 2, sp = idx & 3;      // coarse pixel, subpixel
        int rc = cp / 48, cc = cp % 48;
        int r96 = 2 * rc + (sp >> 1), c96 = 2 * cc + (sp & 1);
        int ir0 = 2 * r96 - 1, ic0 = 2 * c96 - 1;
        bool rok = (r96 > 0), cok = (c96 > 0);
        float acc[8];
        #pragma unroll
        for (int co = 0; co < 8; ++co) acc[co] = 0.0f;
        #pragma unroll 4
        for (int ci = 0; ci < 16; ++ci) {
            const float* base = xpan + ci * 36864;
            float xv[9];
            #pragma unroll
            for (int dr = 0; dr < 3; ++dr) {
                #pragma unroll
                for (int dc = 0; dc < 3; ++dc) {
                    bool ok = (dr > 0 || rok) && (dc > 0 || cok);
                    int off = (ir0 + dr) * 192 + (ic0 + dc);
                    float v = base[ok ? off : 0];
                    xv[dr * 3 + dc] = ok ? v : 0.0f;
                }
            }
            #pragma unroll
            for (int tap = 0; tap < 9; ++tap) {
                #pragma unroll
                for (int co = 0; co < 8; ++co)
                    acc[co] += phw[co * 144 + ci * 9 + tap] * xv[tap];
            }
        }
        #pragma unroll
        for (int co = 0; co < 8; ++co) {
            float v = acc[co];
            v = fmaxf(v, __shfl_xor(v, 1));
            v = fmaxf(v, __shfl_xor(v, 2));
            if (sp == 0) phi_c[cp * 8 + co] = v + phb[co];
        }
    } else if (b < 189) {
        // --- g: 1x1 conv on (16,192,192) -> pool -> (8,96,96) ---
        int idx = (b - 45) * 256 + tid;       // 0..36863
        int op = idx >> 2, sp = idx & 3;      // output pixel (96x96), subpixel
        int r = 2 * (op / 96) + (sp >> 1), c = 2 * (op % 96) + (sp & 1);
        const float* bp = hppan + r * 192 + c;
        float acc[8];
        #pragma unroll
        for (int co = 0; co < 8; ++co) acc[co] = 0.0f;
        #pragma unroll
        for (int ci = 0; ci < 16; ++ci) {
            float xv = bp[ci * 36864];
            #pragma unroll
            for (int co = 0; co < 8; ++co)
                acc[co] += gw[co * 16 + ci] * xv;
        }
        #pragma unroll
        for (int co = 0; co < 8; ++co) {
            float v = acc[co];
            v = fmaxf(v, __shfl_xor(v, 1));
            v = fmaxf(v, __shfl_xor(v, 2));
            if (sp == 0) gmat[op * 8 + co] = v + gb[co];
        }
    } else {
        // --- x_pan passthrough: 589824 f32 = 147456 uint4 = 576 blocks ---
        int i = (b - 189) * 256 + tid;
        ((uint4*)xpan_out)[i] = ((const uint4*)xpan)[i];
    }
}

// ---------------------------------------------------------------------------
// Kernel 2: 4 coarse rows per block. Each wave scans a DISJOINT 576-column
// slice (wave-interleaved) for all 4 rows -> 4x fewer phi reads than
// row-per-wave; no LDS staging (phi served from L2/L3), so no 72KB occupancy
// cap and no bank conflicts. Stable top-2 (value desc, index asc tie-break =
// jax.lax.top_k semantics): in-lane scan -> wave butterfly -> cross-wave
// merge via 256B LDS with explicit (v,i) comparisons (order-independent).
// Top-5 of the fine row = 4 duplicated copies of the coarse max + first fine
// copy of the coarse runner-up; softmax weights collapse accordingly.
// ---------------------------------------------------------------------------
__global__ __launch_bounds__(256) void k2_attn(
    const float* __restrict__ theta_c, const float* __restrict__ phi_c,
    const float* __restrict__ gmat, float* __restrict__ y_c)
{
    const int tid = threadIdx.x;
    const int wv = tid >> 6, lane = tid & 63;
    const int nc0 = blockIdx.x * 4;           // rows nc0..nc0+3

    // block-uniform theta rows -> scalar loads
    float th[4][8];
    #pragma unroll
    for (int r = 0; r < 4; ++r)
        #pragma unroll
        for (int j = 0; j < 8; ++j)
            th[r][j] = theta_c[(nc0 + r) * 8 + j];

    float v1[4], v2[4];
    int i1[4], i2[4];
    #pragma unroll
    for (int r = 0; r < 4; ++r) {
        v1[r] = -INFINITY; v2[r] = -INFINITY;
        i1[r] = 0x7fffffff; i2[r] = 0x7fffffff;
    }

    #pragma unroll
    for (int it = 0; it < 9; ++it) {
        int mc = lane + ((it * 4 + wv) << 6);   // wave-interleaved slices
        const float4* p = (const float4*)(phi_c + mc * 8);
        float4 a = p[0], bq = p[1];
        #pragma unroll
        for (int r = 0; r < 4; ++r) {
            float v = th[r][0] * a.x + th[r][1] * a.y + th[r][2] * a.z + th[r][3] * a.w
                    + th[r][4] * bq.x + th[r][5] * bq.y + th[r][6] * bq.z + th[r][7] * bq.w;
            // per-lane mc ascends with it -> tie keeps earliest index
            if (v > v1[r])      { v2[r] = v1[r]; i2[r] = i1[r]; v1[r] = v; i1[r] = mc; }
            else if (v > v2[r]) { v2[r] = v; i2[r] = mc; }
        }
    }

    // butterfly merge across the wave, per row
    #pragma unroll
    for (int r = 0; r < 4; ++r) {
        #pragma unroll
        for (int off = 1; off < 64; off <<= 1) {
            float ov1 = __shfl_xor(v1[r], off);
            int   oi1 = __shfl_xor(i1[r], off);
            float ov2 = __shfl_xor(v2[r], off);
            int   oi2 = __shfl_xor(i2[r], off);
            bool afirst = (v1[r] > ov1) || (v1[r] == ov1 && i1[r] < oi1);
            if (afirst) {
                bool t = (v2[r] > ov1) || (v2[r] == ov1 && i2[r] < oi1);
                v2[r] = t ? v2[r] : ov1; i2[r] = t ? i2[r] : oi1;
            } else {
                bool t = (ov2 > v1[r]) || (ov2 == v1[r] && oi2 < i1[r]);
                float nv2 = t ? ov2 : v1[r]; int ni2 = t ? oi2 : i1[r];
                v1[r] = ov1; i1[r] = oi1; v2[r] = nv2; i2[r] = ni2;
            }
        }
    }

    // cross-wave merge via LDS (4 waves x 4 rows x top-2)
    __shared__ float cv1[4][4], cv2[4][4];
    __shared__ int   ci1[4][4], ci2[4][4];
    if (lane == 0) {
        #pragma unroll
        for (int r = 0; r < 4; ++r) {
            cv1[wv][r] = v1[r]; ci1[wv][r] = i1[r];
            cv2[wv][r] = v2[r]; ci2[wv][r] = i2[r];
        }
    }
    __syncthreads();

    if (tid < 32) {
        int r = tid >> 3, ch = tid & 7;       // 8 channel-threads per row
        float m1 = -INFINITY, m2 = -INFINITY;
        int j1 = 0x7fffffff, j2 = 0x7fffffff;
        #pragma unroll
        for (int w = 0; w < 4; ++w) {
            #pragma unroll
            for (int s = 0; s < 2; ++s) {
                float v = s ? cv2[w][r] : cv1[w][r];
                int   i = s ? ci2[w][r] : ci1[w][r];
                bool b1 = (v > m1) || (v == m1 && i < j1);
                bool b2 = (v > m2) || (v == m2 && i < j2);
                if (b1)      { m2 = m1; j2 = j1; m1 = v; j1 = i; }
                else if (b2) { m2 = v; j2 = i; }
            }
        }
        int rc1 = j1 / 48, cc1 = j1 % 48;
        int m00 = (2 * rc1) * 96 + 2 * cc1;        // 4 fine copies of argmax
        int rc2 = j2 / 48, cc2 = j2 % 48;
        int mm2 = (2 * rc2) * 96 + 2 * cc2;        // first fine copy of 2nd
        float e = __expf(m2 - m1);
        float inv = 1.0f / (4.0f + e);
        float gs = gmat[m00 * 8 + ch] + gmat[(m00 + 1) * 8 + ch]
                 + gmat[(m00 + 96) * 8 + ch] + gmat[(m00 + 97) * 8 + ch];
        y_c[(nc0 + r) * 8 + ch] = inv * gs + (e * inv) * gmat[mm2 * 8 + ch];
    }
}

// ---------------------------------------------------------------------------
// Kernel 3: wy = W(y)+b per channel (block co owns the whole channel),
// batch stats over the 2304 coarse pixels (== fine stats: y constant over
// 2x2 blocks), normalize, write z upsampled 2x as fp32.
// ---------------------------------------------------------------------------
__global__ __launch_bounds__(256) void k3_out(
    const float* __restrict__ y_c,
    const float* __restrict__ Ww, const float* __restrict__ Wb,
    const float* __restrict__ gamma, const float* __restrict__ beta,
    float* __restrict__ zout)
{
    const int co = blockIdx.x;
    const int tid = threadIdx.x;
    float w[8];
    #pragma unroll
    for (int j = 0; j < 8; ++j) w[j] = Ww[co * 8 + j];
    const float bias = Wb[co];

    float wy[9];
    float s = 0.f, s2 = 0.f;
    #pragma unroll
    for (int j = 0; j < 9; ++j) {
        int mc = tid + j * 256;                 // 2304 = 9*256 exactly
        const float4* p = (const float4*)(y_c + mc * 8);
        float4 a = p[0], bq = p[1];
        float v = bias + w[0] * a.x + w[1] * a.y + w[2] * a.z + w[3] * a.w
                       + w[4] * bq.x + w[5] * bq.y + w[6] * bq.z + w[7] * bq.w;
        wy[j] = v; s += v; s2 += v * v;
    }
    #pragma unroll
    for (int off = 32; off; off >>= 1) {
        s  += __shfl_down(s, off);
        s2 += __shfl_down(s2, off);
    }
    __shared__ float ps[4], ps2[4];
    __shared__ float sc_s, sh_s;
    int wv = tid >> 6, lane = tid & 63;
    if (lane == 0) { ps[wv] = s; ps2[wv] = s2; }
    __syncthreads();
    if (tid == 0) {
        float S  = ps[0] + ps[1] + ps[2] + ps[3];
        float S2 = ps2[0] + ps2[1] + ps2[2] + ps2[3];
        float mean = S * (1.0f / 2304.0f);
        float var  = S2 * (1.0f / 2304.0f) - mean * mean;
        float rsig = 1.0f / sqrtf(var + 1e-5f);
        float gm = gamma[co], be = beta[co];
        sc_s = gm * rsig;
        sh_s = be - mean * gm * rsig;
    }
    __syncthreads();
    float sc = sc_s, sh = sh_s;
    #pragma unroll
    for (int j = 0; j < 9; ++j) {
        int mc = tid + j * 256;
        int rc = mc / 48, cc = mc % 48;
        float zv = wy[j] * sc + sh;
        float2 zz = make_float2(zv, zv);         // 2 adjacent cols, same value
        int base = co * 9216 + (2 * rc) * 96 + 2 * cc;  // even -> 8B aligned
        *(float2*)(zout + base) = zz;
        *(float2*)(zout + base + 96) = zz;
    }
}

extern "C" void kernel_launch(void* const* d_in, const int* in_sizes, int n_in,
                              void* d_out, int out_size, void* d_ws, size_t ws_size,
                              hipStream_t stream) {
    const float* xms   = (const float*)d_in[0];
    const float* hppan = (const float*)d_in[1];
    const float* xpan  = (const float*)d_in[2];
    const float* gw    = (const float*)d_in[3];
    const float* gb    = (const float*)d_in[4];
    const float* thw   = (const float*)d_in[5];
    const float* thb   = (const float*)d_in[6];
    const float* phw   = (const float*)d_in[7];
    const float* phb   = (const float*)d_in[8];
    const float* Ww    = (const float*)d_in[9];
    const float* Wb    = (const float*)d_in[10];
    const float* gam   = (const float*)d_in[11];
    const float* bet   = (const float*)d_in[12];

    float* zout     = (float*)d_out;
    float* xpan_out = zout + Z_ELEMS;

    float* theta_c = (float*)d_ws;              // 18432 f32
    float* phi_c   = theta_c + NC * IC;         // 18432 f32
    float* gmat    = phi_c + NC * IC;           // 73728 f32
    float* y_c     = gmat + NF * IC;            // 18432 f32  (total ~516 KB)

    k1_prep<<<765, 256, 0, stream>>>(xms, hppan, xpan, gw, gb, thw, thb,
                                     phw, phb, theta_c, phi_c, gmat, xpan_out);
    k2_attn<<<576, 256, 0, stream>>>(theta_c, phi_c, gmat, y_c);
    k3_out<<<16, 256, 0, stream>>>(y_c, Ww, Wb, gam, bet, zout);
}

// Round 5
// 113.291 us; speedup vs baseline: 1.0482x; 1.0482x over previous
//
#include <hip/hip_runtime.h>

// Problem constants
#define IC 8
#define NC 2304      // 48*48 coarse pixels (theta rows == phi cols, coarse)
#define NF 9216      // 96*96 fine pixels
#define Z_ELEMS 147456    // 16*96*96
#define XPAN_ELEMS 589824 // 16*192*192

typedef unsigned int uint_t;

// ---------------------------------------------------------------------------
// Kernel 1 (convs only; copy moved to k3's launch):
//   blocks 0..17    theta conv3x3 s2 p1 — 2 threads/output pixel (ci halves)
//   blocks 18..89   phi conv3x3 s2 p1 — 2 threads/PRE-POOL pixel (ci halves)
//                   + shfl ci-merge + shfl-maxpool
//   blocks 90..233  g conv1x1 — 1 thread/PRE-POOL pixel + shfl-maxpool
// All loads unconditional (clamp+select); weights via block-uniform indices
// -> scalar K$ loads; no LDS, no __syncthreads.
// ---------------------------------------------------------------------------
__global__ __launch_bounds__(256) void k1_prep(
    const float* __restrict__ xms,    // (16,96,96)
    const float* __restrict__ hppan,  // (16,192,192)
    const float* __restrict__ xpan,   // (16,192,192)
    const float* __restrict__ gw, const float* __restrict__ gb,
    const float* __restrict__ thw, const float* __restrict__ thb,
    const float* __restrict__ phw, const float* __restrict__ phb,
    float* __restrict__ theta_c,  // [2304][8]
    float* __restrict__ phi_c,    // [2304][8]
    float* __restrict__ gmat)     // [9216][8]
{
    const int b = blockIdx.x;
    const int tid = threadIdx.x;

    if (b < 18) {
        // --- theta: (16,96,96) -> (8,48,48); lane pairs split ci 0-7/8-15 ---
        int idx = b * 256 + tid;              // 0..4607
        int pix = idx >> 1, half = idx & 1;
        int r = pix / 48, c = pix % 48;
        int ir0 = 2 * r - 1, ic0 = 2 * c - 1;
        bool rok = (r > 0), cok = (c > 0);
        float acc[8];
        #pragma unroll
        for (int co = 0; co < 8; ++co) acc[co] = 0.0f;
        int ci0 = half * 8;
        #pragma unroll 4
        for (int ci8 = 0; ci8 < 8; ++ci8) {
            int ci = ci0 + ci8;
            const float* base = xms + ci * 9216;
            float xv[9];
            #pragma unroll
            for (int dr = 0; dr < 3; ++dr) {
                #pragma unroll
                for (int dc = 0; dc < 3; ++dc) {
                    bool ok = (dr > 0 || rok) && (dc > 0 || cok);
                    int off = (ir0 + dr) * 96 + (ic0 + dc);
                    float v = base[ok ? off : 0];
                    xv[dr * 3 + dc] = ok ? v : 0.0f;
                }
            }
            #pragma unroll
            for (int tap = 0; tap < 9; ++tap) {
                #pragma unroll
                for (int co = 0; co < 8; ++co)
                    acc[co] += thw[co * 144 + ci * 9 + tap] * xv[tap];
            }
        }
        #pragma unroll
        for (int co = 0; co < 8; ++co) {
            float v = acc[co] + __shfl_xor(acc[co], 1);   // merge ci halves
            if (half == 0) theta_c[pix * 8 + co] = v + thb[co];
        }
    } else if (b < 90) {
        // --- phi: (16,192,192) -> conv (8,96,96) -> pool (8,48,48) ---
        // lane octets: bit0 = ci half, bits1..2 = pool subpixel
        int idx = (b - 18) * 256 + tid;       // 0..18431
        int half = idx & 1, sp = (idx >> 1) & 3, cp = idx >> 3;
        int rc = cp / 48, cc = cp % 48;
        int r96 = 2 * rc + (sp >> 1), c96 = 2 * cc + (sp & 1);
        int ir0 = 2 * r96 - 1, ic0 = 2 * c96 - 1;
        bool rok = (r96 > 0), cok = (c96 > 0);
        float acc[8];
        #pragma unroll
        for (int co = 0; co < 8; ++co) acc[co] = 0.0f;
        int ci0 = half * 8;
        #pragma unroll 4
        for (int ci8 = 0; ci8 < 8; ++ci8) {
            int ci = ci0 + ci8;
            const float* base = xpan + ci * 36864;
            float xv[9];
            #pragma unroll
            for (int dr = 0; dr < 3; ++dr) {
                #pragma unroll
                for (int dc = 0; dc < 3; ++dc) {
                    bool ok = (dr > 0 || rok) && (dc > 0 || cok);
                    int off = (ir0 + dr) * 192 + (ic0 + dc);
                    float v = base[ok ? off : 0];
                    xv[dr * 3 + dc] = ok ? v : 0.0f;
                }
            }
            #pragma unroll
            for (int tap = 0; tap < 9; ++tap) {
                #pragma unroll
                for (int co = 0; co < 8; ++co)
                    acc[co] += phw[co * 144 + ci * 9 + tap] * xv[tap];
            }
        }
        #pragma unroll
        for (int co = 0; co < 8; ++co) {
            float v = acc[co] + __shfl_xor(acc[co], 1);   // merge ci halves
            v = fmaxf(v, __shfl_xor(v, 2));               // pool cols
            v = fmaxf(v, __shfl_xor(v, 4));               // pool rows
            if ((idx & 7) == 0) phi_c[cp * 8 + co] = v + phb[co];
        }
    } else {
        // --- g: 1x1 conv on (16,192,192) -> pool -> (8,96,96) ---
        int idx = (b - 90) * 256 + tid;       // 0..36863
        int op = idx >> 2, sp = idx & 3;      // output pixel (96x96), subpixel
        int r = 2 * (op / 96) + (sp >> 1), c = 2 * (op % 96) + (sp & 1);
        const float* bp = hppan + r * 192 + c;
        float acc[8];
        #pragma unroll
        for (int co = 0; co < 8; ++co) acc[co] = 0.0f;
        #pragma unroll
        for (int ci = 0; ci < 16; ++ci) {
            float xv = bp[ci * 36864];
            #pragma unroll
            for (int co = 0; co < 8; ++co)
                acc[co] += gw[co * 16 + ci] * xv;
        }
        #pragma unroll
        for (int co = 0; co < 8; ++co) {
            float v = acc[co];
            v = fmaxf(v, __shfl_xor(v, 1));
            v = fmaxf(v, __shfl_xor(v, 2));
            if (sp == 0) gmat[op * 8 + co] = v + gb[co];
        }
    }
}

// ---------------------------------------------------------------------------
// Kernel 2: 4 coarse rows per block. Each wave scans a DISJOINT 576-column
// slice (wave-interleaved) for all 4 rows; phi served from L2/L3. Stable
// top-2 (value desc, index asc tie-break = jax.lax.top_k semantics): in-lane
// scan -> wave butterfly -> cross-wave merge via 256B LDS. Top-5 of the fine
// row = 4 duplicated copies of the coarse max + first fine copy of the coarse
// runner-up; softmax weights collapse accordingly.
// ---------------------------------------------------------------------------
__global__ __launch_bounds__(256) void k2_attn(
    const float* __restrict__ theta_c, const float* __restrict__ phi_c,
    const float* __restrict__ gmat, float* __restrict__ y_c)
{
    const int tid = threadIdx.x;
    const int wv = tid >> 6, lane = tid & 63;
    const int nc0 = blockIdx.x * 4;           // rows nc0..nc0+3

    // block-uniform theta rows -> scalar loads
    float th[4][8];
    #pragma unroll
    for (int r = 0; r < 4; ++r)
        #pragma unroll
        for (int j = 0; j < 8; ++j)
            th[r][j] = theta_c[(nc0 + r) * 8 + j];

    float v1[4], v2[4];
    int i1[4], i2[4];
    #pragma unroll
    for (int r = 0; r < 4; ++r) {
        v1[r] = -INFINITY; v2[r] = -INFINITY;
        i1[r] = 0x7fffffff; i2[r] = 0x7fffffff;
    }

    #pragma unroll
    for (int it = 0; it < 9; ++it) {
        int mc = lane + ((it * 4 + wv) << 6);   // wave-interleaved slices
        const float4* p = (const float4*)(phi_c + mc * 8);
        float4 a = p[0], bq = p[1];
        #pragma unroll
        for (int r = 0; r < 4; ++r) {
            float v = th[r][0] * a.x + th[r][1] * a.y + th[r][2] * a.z + th[r][3] * a.w
                    + th[r][4] * bq.x + th[r][5] * bq.y + th[r][6] * bq.z + th[r][7] * bq.w;
            // per-lane mc ascends with it -> tie keeps earliest index
            if (v > v1[r])      { v2[r] = v1[r]; i2[r] = i1[r]; v1[r] = v; i1[r] = mc; }
            else if (v > v2[r]) { v2[r] = v; i2[r] = mc; }
        }
    }

    // butterfly merge across the wave, per row
    #pragma unroll
    for (int r = 0; r < 4; ++r) {
        #pragma unroll
        for (int off = 1; off < 64; off <<= 1) {
            float ov1 = __shfl_xor(v1[r], off);
            int   oi1 = __shfl_xor(i1[r], off);
            float ov2 = __shfl_xor(v2[r], off);
            int   oi2 = __shfl_xor(i2[r], off);
            bool afirst = (v1[r] > ov1) || (v1[r] == ov1 && i1[r] < oi1);
            if (afirst) {
                bool t = (v2[r] > ov1) || (v2[r] == ov1 && i2[r] < oi1);
                v2[r] = t ? v2[r] : ov1; i2[r] = t ? i2[r] : oi1;
            } else {
                bool t = (ov2 > v1[r]) || (ov2 == v1[r] && oi2 < i1[r]);
                float nv2 = t ? ov2 : v1[r]; int ni2 = t ? oi2 : i1[r];
                v1[r] = ov1; i1[r] = oi1; v2[r] = nv2; i2[r] = ni2;
            }
        }
    }

    // cross-wave merge via LDS (4 waves x 4 rows x top-2)
    __shared__ float cv1[4][4], cv2[4][4];
    __shared__ int   ci1[4][4], ci2[4][4];
    if (lane == 0) {
        #pragma unroll
        for (int r = 0; r < 4; ++r) {
            cv1[wv][r] = v1[r]; ci1[wv][r] = i1[r];
            cv2[wv][r] = v2[r]; ci2[wv][r] = i2[r];
        }
    }
    __syncthreads();

    if (tid < 32) {
        int r = tid >> 3, ch = tid & 7;       // 8 channel-threads per row
        float m1 = -INFINITY, m2 = -INFINITY;
        int j1 = 0x7fffffff, j2 = 0x7fffffff;
        #pragma unroll
        for (int w = 0; w < 4; ++w) {
            #pragma unroll
            for (int s = 0; s < 2; ++s) {
                float v = s ? cv2[w][r] : cv1[w][r];
                int   i = s ? ci2[w][r] : ci1[w][r];
                bool b1 = (v > m1) || (v == m1 && i < j1);
                bool b2 = (v > m2) || (v == m2 && i < j2);
                if (b1)      { m2 = m1; j2 = j1; m1 = v; j1 = i; }
                else if (b2) { m2 = v; j2 = i; }
            }
        }
        int rc1 = j1 / 48, cc1 = j1 % 48;
        int m00 = (2 * rc1) * 96 + 2 * cc1;        // 4 fine copies of argmax
        int rc2 = j2 / 48, cc2 = j2 % 48;
        int mm2 = (2 * rc2) * 96 + 2 * cc2;        // first fine copy of 2nd
        float e = __expf(m2 - m1);
        float inv = 1.0f / (4.0f + e);
        float gs = gmat[m00 * 8 + ch] + gmat[(m00 + 1) * 8 + ch]
                 + gmat[(m00 + 96) * 8 + ch] + gmat[(m00 + 97) * 8 + ch];
        y_c[(nc0 + r) * 8 + ch] = inv * gs + (e * inv) * gmat[mm2 * 8 + ch];
    }
}

// ---------------------------------------------------------------------------
// Kernel 3: blocks 0..15 — wy = W(y)+b per channel, batch stats over the
// 2304 coarse pixels (== fine stats: y constant over 2x2 blocks), normalize,
// write z upsampled 2x. blocks 16..591 — x_pan passthrough copy (runs in
// parallel; independent of BN).
// ---------------------------------------------------------------------------
__global__ __launch_bounds__(256) void k3_out(
    const float* __restrict__ y_c,
    const float* __restrict__ Ww, const float* __restrict__ Wb,
    const float* __restrict__ gamma, const float* __restrict__ beta,
    const float* __restrict__ xpan,
    float* __restrict__ zout, float* __restrict__ xpan_out)
{
    const int b = blockIdx.x;
    const int tid = threadIdx.x;

    if (b >= 16) {
        // --- x_pan passthrough: 589824 f32 = 147456 uint4 = 576 blocks ---
        int i = (b - 16) * 256 + tid;
        ((uint4*)xpan_out)[i] = ((const uint4*)xpan)[i];
        return;
    }

    const int co = b;
    float w[8];
    #pragma unroll
    for (int j = 0; j < 8; ++j) w[j] = Ww[co * 8 + j];
    const float bias = Wb[co];

    float wy[9];
    float s = 0.f, s2 = 0.f;
    #pragma unroll
    for (int j = 0; j < 9; ++j) {
        int mc = tid + j * 256;                 // 2304 = 9*256 exactly
        const float4* p = (const float4*)(y_c + mc * 8);
        float4 a = p[0], bq = p[1];
        float v = bias + w[0] * a.x + w[1] * a.y + w[2] * a.z + w[3] * a.w
                       + w[4] * bq.x + w[5] * bq.y + w[6] * bq.z + w[7] * bq.w;
        wy[j] = v; s += v; s2 += v * v;
    }
    #pragma unroll
    for (int off = 32; off; off >>= 1) {
        s  += __shfl_down(s, off);
        s2 += __shfl_down(s2, off);
    }
    __shared__ float ps[4], ps2[4];
    __shared__ float sc_s, sh_s;
    int wv = tid >> 6, lane = tid & 63;
    if (lane == 0) { ps[wv] = s; ps2[wv] = s2; }
    __syncthreads();
    if (tid == 0) {
        float S  = ps[0] + ps[1] + ps[2] + ps[3];
        float S2 = ps2[0] + ps2[1] + ps2[2] + ps2[3];
        float mean = S * (1.0f / 2304.0f);
        float var  = S2 * (1.0f / 2304.0f) - mean * mean;
        float rsig = 1.0f / sqrtf(var + 1e-5f);
        float gm = gamma[co], be = beta[co];
        sc_s = gm * rsig;
        sh_s = be - mean * gm * rsig;
    }
    __syncthreads();
    float sc = sc_s, sh = sh_s;
    #pragma unroll
    for (int j = 0; j < 9; ++j) {
        int mc = tid + j * 256;
        int rc = mc / 48, cc = mc % 48;
        float zv = wy[j] * sc + sh;
        float2 zz = make_float2(zv, zv);         // 2 adjacent cols, same value
        int base = co * 9216 + (2 * rc) * 96 + 2 * cc;  // even -> 8B aligned
        *(float2*)(zout + base) = zz;
        *(float2*)(zout + base + 96) = zz;
    }
}

extern "C" void kernel_launch(void* const* d_in, const int* in_sizes, int n_in,
                              void* d_out, int out_size, void* d_ws, size_t ws_size,
                              hipStream_t stream) {
    const float* xms   = (const float*)d_in[0];
    const float* hppan = (const float*)d_in[1];
    const float* xpan  = (const float*)d_in[2];
    const float* gw    = (const float*)d_in[3];
    const float* gb    = (const float*)d_in[4];
    const float* thw   = (const float*)d_in[5];
    const float* thb   = (const float*)d_in[6];
    const float* phw   = (const float*)d_in[7];
    const float* phb   = (const float*)d_in[8];
    const float* Ww    = (const float*)d_in[9];
    const float* Wb    = (const float*)d_in[10];
    const float* gam   = (const float*)d_in[11];
    const float* bet   = (const float*)d_in[12];

    float* zout     = (float*)d_out;
    float* xpan_out = zout + Z_ELEMS;

    float* theta_c = (float*)d_ws;              // 18432 f32
    float* phi_c   = theta_c + NC * IC;         // 18432 f32
    float* gmat    = phi_c + NC * IC;           // 73728 f32
    float* y_c     = gmat + NF * IC;            // 18432 f32  (total ~516 KB)

    k1_prep<<<234, 256, 0, stream>>>(xms, hppan, xpan, gw, gb, thw, thb,
                                     phw, phb, theta_c, phi_c, gmat);
    k2_attn<<<576, 256, 0, stream>>>(theta_c, phi_c, gmat, y_c);
    k3_out<<<592, 256, 0, stream>>>(y_c, Ww, Wb, gam, bet, xpan,
                                    zout, xpan_out);
}